// Round 16
// baseline (5742.637 us; speedup 1.0000x reference)
//
#include <hip/hip_runtime.h>

#define BB 32
#define NN 16384
#define CC 64
#define NC 4096
#define T  512             // 8 waves/block
#define SLOTS (NN / T)     // 32 points per thread

// ---------------------------------------------------------------------------
// FPS, one block per batch. Distance chain B1 = fma(dz,dz, fma(dx,dx, dy*dy))
// — bitwise-verified vs reference (R6 pass, absmax 0).
// R16: state as 128 NAMED SCALARS (macro-generated), not arrays.
//   R11-R15 showed VGPR_Count stuck at 84 for 128 floats of state across
//   every structural variant -> the arrays are demoted (alloca/scratch or
//   reload) before regalloc. Named scalars are SSA by construction: regalloc
//   must home them in registers. T=512 + launch_bounds(512,1) = 256+ unified
//   regs budget; state+temps ~170 fits.
// Proven pieces kept: DPP wave-max (row_shr 1/2/4/8 + bcast 15/31) + single
// LDS atomicMax on float bits (dist>=0 -> bit order == float order) [R14];
// achievers rescan descending + atomicMin = numpy first-occurrence argmax
// [R7+]; compact 12B-row centroid buffer in d_ws, L2-resident [R12];
// depth-4 sentinel rotation, reset slot (it+2)&3 [R13+].
// ---------------------------------------------------------------------------

#define FOR32(M) M(0) M(1) M(2) M(3) M(4) M(5) M(6) M(7) \
                 M(8) M(9) M(10) M(11) M(12) M(13) M(14) M(15) \
                 M(16) M(17) M(18) M(19) M(20) M(21) M(22) M(23) \
                 M(24) M(25) M(26) M(27) M(28) M(29) M(30) M(31)
#define FOR32R(M) M(31) M(30) M(29) M(28) M(27) M(26) M(25) M(24) \
                  M(23) M(22) M(21) M(20) M(19) M(18) M(17) M(16) \
                  M(15) M(14) M(13) M(12) M(11) M(10) M(9) M(8) \
                  M(7) M(6) M(5) M(4) M(3) M(2) M(1) M(0)

template <int CTRL>
__device__ __forceinline__ float dpp_max(float x) {
    const int yi = __builtin_amdgcn_update_dpp(0, __float_as_int(x),
                                               CTRL, 0xf, 0xf, true);
    return fmaxf(x, __int_as_float(yi));
}

__device__ __forceinline__ float wave_max_dpp(float x) {
    x = dpp_max<0x111>(x);   // row_shr:1
    x = dpp_max<0x112>(x);   // row_shr:2
    x = dpp_max<0x114>(x);   // row_shr:4
    x = dpp_max<0x118>(x);   // row_shr:8
    x = dpp_max<0x142>(x);   // row_bcast:15
    x = dpp_max<0x143>(x);   // row_bcast:31
    return x;                // valid in lane 63
}

// cbase/cstride: centroid re-read source (compact: stride 3; fallback: 64).
__global__ __launch_bounds__(T, 1) void fps_kernel(const float* __restrict__ in,
                                                   float* __restrict__ out,
                                                   const float* __restrict__ cb0,
                                                   int cstride) {
#pragma clang fp contract(off)
    const int b    = blockIdx.x;
    const int t    = threadIdx.x;
    const int lane = t & 63;

    __shared__ unsigned s_gbits4[4];
    __shared__ int      s_far4[4];

    const float* base = in + (size_t)b * NN * CC;
    const float* cb   = cb0 + (size_t)b * NN * cstride;

#define DECL(i) float x##i, y##i, z##i, d##i;
    FOR32(DECL)
#undef DECL

#define INIT(i) { const float4 v = *reinterpret_cast<const float4*>( \
                      base + (size_t)((i) * T + t) * CC);            \
                  x##i = v.x; y##i = v.y; z##i = v.z; d##i = 1e10f; }
    FOR32(INIT)
#undef INIT

    if (t < 4) { s_far4[t] = 0x7fffffff; s_gbits4[t] = 0u; }

    float cx = base[0], cy = base[1], cz = base[2];   // point 0
    int   far = 0;
    __syncthreads();

    int* idx_out = reinterpret_cast<int*>(out);

    for (int it = 0; it < NC; ++it) {
        if (t == 0) idx_out[((size_t)b * NC + it) * CC] = far;
        if (it == NC - 1) break;

        // ---- dist update (chain B1, bitwise-exact) ----
#define UPD(i) { const float dx = x##i - cx;                          \
                 const float dy = y##i - cy;                          \
                 const float dz = z##i - cz;                          \
                 const float dd = fmaf(dz, dz, fmaf(dx, dx, dy * dy)); \
                 d##i = fminf(d##i, dd); }
        FOR32(UPD)
#undef UPD

        // ---- 4-accumulator max tree over d0..d31 ----
        float a0 = fmaxf(fmaxf(fmaxf(d0,  d1),  fmaxf(d2,  d3)),
                         fmaxf(fmaxf(d4,  d5),  fmaxf(d6,  d7)));
        float a1 = fmaxf(fmaxf(fmaxf(d8,  d9),  fmaxf(d10, d11)),
                         fmaxf(fmaxf(d12, d13), fmaxf(d14, d15)));
        float a2 = fmaxf(fmaxf(fmaxf(d16, d17), fmaxf(d18, d19)),
                         fmaxf(fmaxf(d20, d21), fmaxf(d22, d23)));
        float a3 = fmaxf(fmaxf(fmaxf(d24, d25), fmaxf(d26, d27)),
                         fmaxf(fmaxf(d28, d29), fmaxf(d30, d31)));
        const float lv = fmaxf(fmaxf(a0, a1), fmaxf(a2, a3));

        // ---- wave64 max via DPP; lane 63 -> LDS atomicMax on bits ----
        const float wv = wave_max_dpp(lv);
        if (lane == 63)
            atomicMax(&s_gbits4[it & 3], __float_as_uint(wv));

        if (t == 0) {              // reset slot used 2 iters ahead (barrier-safe)
            s_far4[(it + 2) & 3]   = 0x7fffffff;
            s_gbits4[(it + 2) & 3] = 0u;
        }
        __syncthreads();                                  // A

        const float gm = __uint_as_float(s_gbits4[it & 3]);

        // ---- achievers: first local index (descending scan), atomicMin ----
        if (lv == gm) {
            int myi = 0x7fffffff;
#define SCAN(i) myi = (d##i == gm) ? ((i) * T + t) : myi;
            FOR32R(SCAN)
#undef SCAN
            atomicMin(&s_far4[it & 3], myi);
        }
        __syncthreads();                                  // B

        far = s_far4[it & 3];

        // ---- centroid reload (compact L2-resident buffer, or strided) ----
        cx = cb[(size_t)far * cstride + 0];
        cy = cb[(size_t)far * cstride + 1];
        cz = cb[(size_t)far * cstride + 2];
    }
}

// ---------------------------------------------------------------------------
// One-time xyz compaction: in[b][i][0..2] -> cpts[b][i*3+{0,1,2}] (12B rows).
// ---------------------------------------------------------------------------
__global__ __launch_bounds__(256) void compact_kernel(const float* __restrict__ in,
                                                      float* __restrict__ cpts) {
    const int gid = blockIdx.x * blockDim.x + threadIdx.x;   // one point each
    const int b   = gid >> 14;                               // NN == 16384
    const int i   = gid & (NN - 1);
    const float* src = in + ((size_t)b * NN + i) * CC;
    float* dst = cpts + ((size_t)b * NN + i) * 3;
    dst[0] = src[0];
    dst[1] = src[1];
    dst[2] = src[2];
}

// ---------------------------------------------------------------------------
// Gather kernel: one wave64 per output row (64 channels).
// ---------------------------------------------------------------------------
__global__ __launch_bounds__(256) void gather_kernel(const float* __restrict__ in,
                                                     float* out) {
    const int gid  = blockIdx.x * blockDim.x + threadIdx.x;
    const int row  = gid >> 6;     // 0 .. B*NC-1
    const int lane = gid & 63;     // channel
    const int b = row >> 12;       // NC == 4096
    const int idx = reinterpret_cast<const int*>(out)[(size_t)row * CC];
    const float v = in[((size_t)b * NN + idx) * CC + lane];
    out[(size_t)row * CC + lane] = v;
}

extern "C" void kernel_launch(void* const* d_in, const int* in_sizes, int n_in,
                              void* d_out, int out_size, void* d_ws, size_t ws_size,
                              hipStream_t stream) {
    const float* in = (const float*)d_in[0];
    float* out = (float*)d_out;

    const size_t ws_need = (size_t)BB * NN * 3 * sizeof(float);   // 6 MB
    if (ws_size >= ws_need) {
        float* cpts = (float*)d_ws;
        compact_kernel<<<(BB * NN) / 256, 256, 0, stream>>>(in, cpts);
        fps_kernel<<<BB, T, 0, stream>>>(in, out, cpts, 3);
    } else {
        fps_kernel<<<BB, T, 0, stream>>>(in, out, in, CC);
    }

    const int total = BB * NC * CC;          // 8,388,608
    gather_kernel<<<total / 256, 256, 0, stream>>>(in, out);
}

// Round 17
// 5334.460 us; speedup vs baseline: 1.0765x; 1.0765x over previous
//
#include <hip/hip_runtime.h>

#define BB 32
#define NN 16384
#define CC 64
#define NC 4096
#define T  512             // 8 waves/block = exactly 2 waves/SIMD on one CU
#define SLOTS (NN / T)     // 32 points per thread

// ---------------------------------------------------------------------------
// FPS, one block per batch (R10: cross-block sync ~4.6us/iter via L3 = dead).
// Distance chain B1 = fma(dz,dz, fma(dx,dx, dy*dy)) — bitwise-verified (R6).
// R17 vs R14 (structure identical, R14 = best 5.33ms):
//   * __attribute__((amdgpu_waves_per_eu(2,2))): clamps the backend's
//     occupancy TARGET to exactly 2 waves/EU -> 256-reg unified budget,
//     bidirectional. launch_bounds' 2nd arg only sets the MIN; R7-R16 showed
//     the allocator squeezing arch VGPRs to 84-88 (AGPR-homing / remat-
//     reloading ~100 state values, ~2x inst inflation) regardless of min.
//   * one-time asm "+v" pins after init: state values become asm results ->
//     not rematerializable from the global loads (blocks reload-spills).
// Proven pieces kept: DPP wave-max (row_shr 1/2/4/8 + bcast 15/31) + single
// LDS atomicMax on float bits (dist>=0 -> bit order == float order) [R14];
// achievers rescan descending + atomicMin = numpy first-occurrence argmax
// [R7+]; compact 12B-row centroid buffer in d_ws, L2-resident [R12];
// depth-4 sentinel rotation, reset slot (it+2)&3 [R13+].
// ---------------------------------------------------------------------------

template <int CTRL>
__device__ __forceinline__ float dpp_max(float x) {
    const int yi = __builtin_amdgcn_update_dpp(0, __float_as_int(x),
                                               CTRL, 0xf, 0xf, true);
    return fmaxf(x, __int_as_float(yi));
}

__device__ __forceinline__ float wave_max_dpp(float x) {
    x = dpp_max<0x111>(x);   // row_shr:1
    x = dpp_max<0x112>(x);   // row_shr:2
    x = dpp_max<0x114>(x);   // row_shr:4
    x = dpp_max<0x118>(x);   // row_shr:8
    x = dpp_max<0x142>(x);   // row_bcast:15
    x = dpp_max<0x143>(x);   // row_bcast:31
    return x;                // valid in lane 63
}

__global__ __launch_bounds__(T)
__attribute__((amdgpu_waves_per_eu(2, 2)))
void fps_kernel(const float* __restrict__ in,
                float* __restrict__ out,
                const float* __restrict__ cpts) {
#pragma clang fp contract(off)
    const int b    = blockIdx.x;
    const int t    = threadIdx.x;
    const int lane = t & 63;

    __shared__ unsigned s_gbits4[4];
    __shared__ int      s_far4[4];

    const float* base = in + (size_t)b * NN * CC;
    const float* cb   = cpts + (size_t)b * NN * 3;

    float px[SLOTS], py[SLOTS], pz[SLOTS], dist[SLOTS];
#pragma unroll
    for (int j = 0; j < SLOTS; ++j) {
        const int i = j * T + t;
        const float4 v = *reinterpret_cast<const float4*>(base + (size_t)i * CC);
        px[j] = v.x; py[j] = v.y; pz[j] = v.z;
        dist[j] = 1e10f;
    }
    // One-time pins: state becomes asm-defined -> cannot be remat-reloaded.
#pragma unroll
    for (int j = 0; j < SLOTS; ++j) {
        asm("" : "+v"(px[j]), "+v"(py[j]), "+v"(pz[j]), "+v"(dist[j]));
    }
    if (t < 4) { s_far4[t] = 0x7fffffff; s_gbits4[t] = 0u; }

    float cx = base[0], cy = base[1], cz = base[2];   // point 0
    int   far = 0;
    __syncthreads();

    int* idx_out = reinterpret_cast<int*>(out);

    for (int it = 0; it < NC; ++it) {
        if (t == 0) idx_out[((size_t)b * NC + it) * CC] = far;
        if (it == NC - 1) break;

        // ---- dist update (chain B1, bitwise-exact) + running value max ----
        float lv = -1.0f;
#pragma unroll
        for (int j = 0; j < SLOTS; ++j) {
            const float dx = px[j] - cx;
            const float dy = py[j] - cy;
            const float dz = pz[j] - cz;
            const float d  = fmaf(dz, dz, fmaf(dx, dx, dy * dy));
            const float nd = fminf(dist[j], d);
            dist[j] = nd;
            lv = fmaxf(lv, nd);
        }

        // ---- wave64 max via DPP; lane 63 -> LDS atomicMax on bits ----
        const float wv = wave_max_dpp(lv);
        if (lane == 63)
            atomicMax(&s_gbits4[it & 3], __float_as_uint(wv));

        if (t == 0) {              // reset slot used 2 iters ahead (barrier-safe)
            s_far4[(it + 2) & 3]   = 0x7fffffff;
            s_gbits4[(it + 2) & 3] = 0u;
        }
        __syncthreads();                                  // A

        const float gm = __uint_as_float(s_gbits4[it & 3]);

        // ---- achievers: first local index (descending), atomicMin ----
        if (lv == gm) {
            int myi = 0x7fffffff;
#pragma unroll
            for (int j = SLOTS - 1; j >= 0; --j)
                myi = (dist[j] == gm) ? (j * T + t) : myi;
            atomicMin(&s_far4[it & 3], myi);
        }
        __syncthreads();                                  // B

        far = s_far4[it & 3];

        // ---- centroid reload from compact L2-resident buffer ----
        cx = cb[(size_t)far * 3 + 0];
        cy = cb[(size_t)far * 3 + 1];
        cz = cb[(size_t)far * 3 + 2];
    }
}

// ---------------------------------------------------------------------------
// One-time xyz compaction: in[b][i][0..2] -> cpts[b][i*3+{0,1,2}] (12B rows).
// ---------------------------------------------------------------------------
__global__ __launch_bounds__(256) void compact_kernel(const float* __restrict__ in,
                                                      float* __restrict__ cpts) {
    const int gid = blockIdx.x * blockDim.x + threadIdx.x;   // one point each
    const int b   = gid >> 14;                               // NN == 16384
    const int i   = gid & (NN - 1);
    const float* src = in + ((size_t)b * NN + i) * CC;
    float* dst = cpts + ((size_t)b * NN + i) * 3;
    dst[0] = src[0];
    dst[1] = src[1];
    dst[2] = src[2];
}

// ---------------------------------------------------------------------------
// Fallback (ws too small): centroid reloads hit the strided input directly.
// ---------------------------------------------------------------------------
__global__ __launch_bounds__(T)
__attribute__((amdgpu_waves_per_eu(2, 2)))
void fps_fallback(const float* __restrict__ in,
                  float* __restrict__ out) {
#pragma clang fp contract(off)
    const int b    = blockIdx.x;
    const int t    = threadIdx.x;
    const int lane = t & 63;

    __shared__ unsigned s_gbits4[4];
    __shared__ int      s_far4[4];

    const float* base = in + (size_t)b * NN * CC;

    float px[SLOTS], py[SLOTS], pz[SLOTS], dist[SLOTS];
#pragma unroll
    for (int j = 0; j < SLOTS; ++j) {
        const int i = j * T + t;
        const float4 v = *reinterpret_cast<const float4*>(base + (size_t)i * CC);
        px[j] = v.x; py[j] = v.y; pz[j] = v.z;
        dist[j] = 1e10f;
    }
#pragma unroll
    for (int j = 0; j < SLOTS; ++j) {
        asm("" : "+v"(px[j]), "+v"(py[j]), "+v"(pz[j]), "+v"(dist[j]));
    }
    if (t < 4) { s_far4[t] = 0x7fffffff; s_gbits4[t] = 0u; }

    float cx = base[0], cy = base[1], cz = base[2];
    int   far = 0;
    __syncthreads();

    int* idx_out = reinterpret_cast<int*>(out);

    for (int it = 0; it < NC; ++it) {
        if (t == 0) idx_out[((size_t)b * NC + it) * CC] = far;
        if (it == NC - 1) break;

        float lv = -1.0f;
#pragma unroll
        for (int j = 0; j < SLOTS; ++j) {
            const float dx = px[j] - cx;
            const float dy = py[j] - cy;
            const float dz = pz[j] - cz;
            const float d  = fmaf(dz, dz, fmaf(dx, dx, dy * dy));
            const float nd = fminf(dist[j], d);
            dist[j] = nd;
            lv = fmaxf(lv, nd);
        }

        const float wv = wave_max_dpp(lv);
        if (lane == 63)
            atomicMax(&s_gbits4[it & 3], __float_as_uint(wv));

        if (t == 0) {
            s_far4[(it + 2) & 3]   = 0x7fffffff;
            s_gbits4[(it + 2) & 3] = 0u;
        }
        __syncthreads();

        const float gm = __uint_as_float(s_gbits4[it & 3]);

        if (lv == gm) {
            int myi = 0x7fffffff;
#pragma unroll
            for (int j = SLOTS - 1; j >= 0; --j)
                myi = (dist[j] == gm) ? (j * T + t) : myi;
            atomicMin(&s_far4[it & 3], myi);
        }
        __syncthreads();

        far = s_far4[it & 3];
        cx = base[(size_t)far * CC + 0];
        cy = base[(size_t)far * CC + 1];
        cz = base[(size_t)far * CC + 2];
    }
}

// ---------------------------------------------------------------------------
// Gather kernel: one wave64 per output row (64 channels).
// ---------------------------------------------------------------------------
__global__ __launch_bounds__(256) void gather_kernel(const float* __restrict__ in,
                                                     float* out) {
    const int gid  = blockIdx.x * blockDim.x + threadIdx.x;
    const int row  = gid >> 6;     // 0 .. B*NC-1
    const int lane = gid & 63;     // channel
    const int b = row >> 12;       // NC == 4096
    const int idx = reinterpret_cast<const int*>(out)[(size_t)row * CC];
    const float v = in[((size_t)b * NN + idx) * CC + lane];
    out[(size_t)row * CC + lane] = v;
}

extern "C" void kernel_launch(void* const* d_in, const int* in_sizes, int n_in,
                              void* d_out, int out_size, void* d_ws, size_t ws_size,
                              hipStream_t stream) {
    const float* in = (const float*)d_in[0];
    float* out = (float*)d_out;

    const size_t ws_need = (size_t)BB * NN * 3 * sizeof(float);   // 6 MB
    if (ws_size >= ws_need) {
        float* cpts = (float*)d_ws;
        compact_kernel<<<(BB * NN) / 256, 256, 0, stream>>>(in, cpts);
        fps_kernel<<<BB, T, 0, stream>>>(in, out, cpts);
    } else {
        fps_fallback<<<BB, T, 0, stream>>>(in, out);
    }

    const int total = BB * NC * CC;          // 8,388,608
    gather_kernel<<<total / 256, 256, 0, stream>>>(in, out);
}